// Round 9
// baseline (263.119 us; speedup 1.0000x reference)
//
#include <hip/hip_runtime.h>

// ---------------------------------------------------------------------------
// Fused NeRF MLP forward: 262144 rows, 63-in, 8x256 hidden + skip at L4->L5,
// 4-dim output. R9: hidden layers moved to 32x32x16 f16 MFMA (swapped
// operands), fp32 accum. vs R8 (16x16x32): -13% matrix-pipe cycles (ubench
// 2382 vs 2075 TF) and half the MFMA instruction count per wave-layer.
//   A = W-frag: m = lane&31 (ncol-within-32), k = 16ks + 8*(lane>>5) + i
//   B = h-frag: n = lane&31 (sample),        k same slots (bijection symmetry)
//   D (m101): col = lane&31 = sample, row = (reg&3)+8*(reg>>2)+4*(lane>>5)
//     -> reg quad q holds 4 consecutive ncols cf*32+8q+4hi+r: b64-packed
//        epilogue + f4 bias-init preserved from R8.
// Wave tile: 64 ncols (slots 2wid,2wid+1) x 64 samples (sf 0,1); 16 ks/layer.
// Weight file: same bytes & offsets, re-indexed (ks,slot 0..7) 32-wide frags;
// out-layer keeps the proven 16x16 path. Depth-3 W prefetch, nodrain
// barriers, setprio retained (proven-neutral-or-better).
// ---------------------------------------------------------------------------

typedef _Float16 h8 __attribute__((ext_vector_type(8)));
typedef float f4 __attribute__((ext_vector_type(4)));
typedef float f16v __attribute__((ext_vector_type(16)));

// per-layer halves: L0 4ks*4096, L1-L4/L6/L7 16ks*4096, L5 20ks*4096, OUT 8*512
#define OFF_L0   0
#define OFF_L1   16384
#define OFF_L2   81920
#define OFF_L3   147456
#define OFF_L4   212992
#define OFF_L5   278528
#define OFF_L6   360448
#define OFF_L7   425984
#define OFF_OUT  491520
#define TOT_HALVES 495616
#define TOT_GROUPS (TOT_HALVES / 8)   // 61952

__global__ void nerf_prep(const float* __restrict__ W0, const float* __restrict__ W1,
                          const float* __restrict__ W2, const float* __restrict__ W3,
                          const float* __restrict__ W4, const float* __restrict__ W5,
                          const float* __restrict__ W6, const float* __restrict__ W7,
                          const float* __restrict__ Wout, _Float16* __restrict__ wf)
{
    int g = blockIdx.x * 256 + threadIdx.x;     // one 8-half fragment group
    if (g >= TOT_GROUPS) return;

    const int bounds[10] = {0, 2048, 10240, 18432, 26624, 34816, 45056, 53248, 61440, 61952};
    const float* Ws[9] = {W0, W1, W2, W3, W4, W5, W6, W7, Wout};

    int L = 0;
    while (L < 8 && g >= bounds[L + 1]) ++L;

    int t    = g - bounds[L];
    int lane = t & 63;
    int q    = t >> 6;
    int n, k0;
    if (L == 8) {                       // out layer: 16x16x32 format (unchanged)
        n  = lane & 15;
        k0 = q * 32 + (lane >> 4) * 8;
    } else {                            // hidden: 32x32x16 format
        int slot = q & 7;               // 32-col fragment index
        int ks   = q >> 3;              // K/16 step
        n  = slot * 32 + (lane & 31);
        k0 = ks * 16 + (lane >> 5) * 8;
    }

    const float* W = Ws[L];
    h8 v;
#pragma unroll
    for (int i = 0; i < 8; ++i) {
        int k = k0 + i;
        float val = 0.f;
        if (L == 0) {
            if (k < 63) val = W[k * 256 + n];                 // 63x256, pad k=63
        } else if (L == 5) {
            // k' < 256 -> h part (orig row 63+k'); k' >= 256 -> x part (orig row k'-256)
            if (k < 256)             val = W[(63 + k) * 256 + n];
            else if ((k - 256) < 63) val = W[(k - 256) * 256 + n];
        } else if (L == 8) {
            if (n < 4) val = W[k * 4 + n];                    // 256x4, pad n to 16
        } else {
            val = W[k * 256 + n];                             // 256x256
        }
        v[i] = (_Float16)val;
    }
    *(h8*)(wf + (size_t)g * 8) = v;
}

// 32-shape fragment pointer: slot in [0,8) = which 32-col fragment
__device__ __forceinline__ const h8* bfrag32(const _Float16* __restrict__ w,
                                             int ks, int slot, int lane)
{
    return (const h8*)(w + (size_t)((ks * 8 + slot) * 64 + lane) * 8);
}

// Barrier without vmcnt drain (keeps cross-layer W-prefetch in flight).
__device__ __forceinline__ void barrier_nodrain()
{
    asm volatile("s_waitcnt lgkmcnt(0)" ::: "memory");
    __builtin_amdgcn_s_barrier();
    __builtin_amdgcn_sched_barrier(0);
}

// MODE: 0 = h from hbuf, 1 = from xbuf (L0), 2 = hbuf then xbuf (L5 skip)
// pf[3][2]: depth-3 rolling W prefetch (slot = global kstep % 3, GB3 = base%3)
template <int KSTEPS, int MODE, int GB3, bool LAST>
__device__ __forceinline__ void mlp_layer(_Float16 (&hbuf)[64][264], _Float16 (&xbuf)[64][72],
                                          const _Float16* __restrict__ wfrag,
                                          const _Float16* __restrict__ wnext,
                                          const float* __restrict__ bias,
                                          int wid, int lane, h8 (&pf)[3][2])
{
    const int l31 = lane & 31, hi = lane >> 5;

    // acc init = bias. ncol = wid*64 + cf*32 + q*8 + hi*4 + r  (16B-aligned f4)
    f16v acc[2][2];   // [cf][sf]
#pragma unroll
    for (int cf = 0; cf < 2; ++cf) {
#pragma unroll
        for (int q = 0; q < 4; ++q) {
            f4 b4 = *(const f4*)&bias[wid * 64 + cf * 32 + q * 8 + hi * 4];
#pragma unroll
            for (int r = 0; r < 4; ++r) {
                acc[cf][0][q * 4 + r] = b4[r];
                acc[cf][1][q * 4 + r] = b4[r];
            }
        }
    }

#pragma unroll
    for (int ks = 0; ks < KSTEPS; ++ks) {
        const int slot = (GB3 + ks) % 3;      // constant after unroll
        h8 hfr[2];
#pragma unroll
        for (int sf = 0; sf < 2; ++sf) {
            const _Float16* ap;
            if constexpr (MODE == 1) {
                ap = &xbuf[sf * 32 + l31][ks * 16 + hi * 8];
            } else if constexpr (MODE == 2) {
                ap = (ks < 16) ? &hbuf[sf * 32 + l31][ks * 16 + hi * 8]
                               : &xbuf[sf * 32 + l31][(ks - 16) * 16 + hi * 8];
            } else {
                ap = &hbuf[sf * 32 + l31][ks * 16 + hi * 8];
            }
            hfr[sf] = *(const h8*)ap;
        }
        __builtin_amdgcn_s_setprio(1);
#pragma unroll
        for (int cf = 0; cf < 2; ++cf)
#pragma unroll
            for (int sf = 0; sf < 2; ++sf)
                acc[cf][sf] = __builtin_amdgcn_mfma_f32_32x32x16_f16(pf[slot][cf], hfr[sf], acc[cf][sf], 0, 0, 0);
        __builtin_amdgcn_s_setprio(0);
        // refill consumed slot with global kstep g+3
        if (ks + 3 < KSTEPS) {
#pragma unroll
            for (int cf = 0; cf < 2; ++cf)
                pf[slot][cf] = *bfrag32(wfrag, ks + 3, wid * 2 + cf, lane);
        } else {
            if constexpr (!LAST) {
#pragma unroll
                for (int cf = 0; cf < 2; ++cf)
                    pf[slot][cf] = *bfrag32(wnext, ks + 3 - KSTEPS, wid * 2 + cf, lane);
            }
        }
    }

    barrier_nodrain();   // WAR: all reads of hbuf done

    // epilogue: D[ncol][sample]; reg q*4+r -> ncol cf*32+8q+4hi+r, sample sf*32+l31
#pragma unroll
    for (int cf = 0; cf < 2; ++cf) {
#pragma unroll
        for (int sf = 0; sf < 2; ++sf) {
#pragma unroll
            for (int q = 0; q < 4; ++q) {
                union { _Float16 h[4]; unsigned long long u; } p;
#pragma unroll
                for (int r = 0; r < 4; ++r)
                    p.h[r] = (_Float16)fmaxf(acc[cf][sf][q * 4 + r], 0.f);
                *(unsigned long long*)&hbuf[sf * 32 + l31][wid * 64 + cf * 32 + q * 8 + hi * 4] = p.u;
            }
        }
    }
    barrier_nodrain();   // RAW: writes visible before next layer reads
}

__global__ __launch_bounds__(256, 3) void nerf_fused(
    const float* __restrict__ x,
    const float* __restrict__ b0, const float* __restrict__ b1, const float* __restrict__ b2,
    const float* __restrict__ b3, const float* __restrict__ b4, const float* __restrict__ b5,
    const float* __restrict__ b6, const float* __restrict__ b7, const float* __restrict__ bout,
    const _Float16* __restrict__ wf,
    float* __restrict__ out)
{
    __shared__ _Float16 hbuf[64][264];   // proven padded layout
    __shared__ _Float16 xbuf[64][72];

    const int tid  = threadIdx.x;
    const int wid  = tid >> 6;
    const int lane = tid & 63;
    const int lg   = lane >> 4, ln = lane & 15;
    const int row0 = blockIdx.x * 64;

    // prologue: globals 0,1,2 = L0 ks0,ks1,ks2 into slots 0,1,2
    h8 pf[3][2];
#pragma unroll
    for (int cf = 0; cf < 2; ++cf) {
        pf[0][cf] = *bfrag32(wf + OFF_L0, 0, wid * 2 + cf, lane);
        pf[1][cf] = *bfrag32(wf + OFF_L0, 1, wid * 2 + cf, lane);
        pf[2][cf] = *bfrag32(wf + OFF_L0, 2, wid * 2 + cf, lane);
    }

    // stage x[:, 0:63] -> fp16, zero-pad col 63
    for (int idx = tid; idx < 64 * 64; idx += 256) {
        int r = idx >> 6, c = idx & 63;
        float v = (c < 63) ? x[(size_t)(row0 + r) * 90 + c] : 0.f;
        xbuf[r][c] = (_Float16)v;
    }
    barrier_nodrain();

    // gbase (in 16-wide ks units): 0,4,20,36,52,68,88,104 -> %3:
    mlp_layer<4,  1, 0, false>(hbuf, xbuf, wf + OFF_L0, wf + OFF_L1, b0, wid, lane, pf);
    mlp_layer<16, 0, 1, false>(hbuf, xbuf, wf + OFF_L1, wf + OFF_L2, b1, wid, lane, pf);
    mlp_layer<16, 0, 2, false>(hbuf, xbuf, wf + OFF_L2, wf + OFF_L3, b2, wid, lane, pf);
    mlp_layer<16, 0, 0, false>(hbuf, xbuf, wf + OFF_L3, wf + OFF_L4, b3, wid, lane, pf);
    mlp_layer<16, 0, 1, false>(hbuf, xbuf, wf + OFF_L4, wf + OFF_L5, b4, wid, lane, pf);
    mlp_layer<20, 2, 2, false>(hbuf, xbuf, wf + OFF_L5, wf + OFF_L6, b5, wid, lane, pf);
    mlp_layer<16, 0, 1, false>(hbuf, xbuf, wf + OFF_L6, wf + OFF_L7, b6, wid, lane, pf);
    mlp_layer<16, 0, 2, true >(hbuf, xbuf, wf + OFF_L7, wf + OFF_L7, b7, wid, lane, pf);

    // output layer 256 -> 4: proven 16x16x32 path, wave wid owns rows [16wid,16wid+16)
    f4 oacc;
#pragma unroll
    for (int i = 0; i < 4; ++i) oacc[i] = 0.f;
#pragma unroll
    for (int ks = 0; ks < 8; ++ks) {
        h8 bfr = *(const h8*)(wf + OFF_OUT + (size_t)(ks * 64 + lane) * 8);
        h8 afr = *(const h8*)&hbuf[wid * 16 + ln][ks * 32 + lg * 8];
        oacc = __builtin_amdgcn_mfma_f32_16x16x32_f16(afr, bfr, oacc, 0, 0, 0);
    }
    if (ln < 4) {
        float bo = bout[ln];
#pragma unroll
        for (int i = 0; i < 4; ++i) {
            int r = row0 + wid * 16 + lg * 4 + i;
            out[(size_t)r * 4 + ln] = oacc[i] + bo;
        }
    }
}

extern "C" void kernel_launch(void* const* d_in, const int* in_sizes, int n_in,
                              void* d_out, int out_size, void* d_ws, size_t ws_size,
                              hipStream_t stream)
{
    const float* x = (const float*)d_in[0];
    const float* W[9];
    const float* b[9];
    for (int i = 0; i < 8; ++i) {
        W[i] = (const float*)d_in[1 + 2 * i];
        b[i] = (const float*)d_in[2 + 2 * i];
    }
    W[8] = (const float*)d_in[17];   // Wout
    b[8] = (const float*)d_in[18];   // bout

    _Float16* wf = (_Float16*)d_ws;

    nerf_prep<<<(TOT_GROUPS + 255) / 256, 256, 0, stream>>>(
        W[0], W[1], W[2], W[3], W[4], W[5], W[6], W[7], W[8], wf);

    nerf_fused<<<262144 / 64, 256, 0, stream>>>(
        x, b[0], b[1], b[2], b[3], b[4], b[5], b[6], b[7], b[8], wf,
        (float*)d_out);
}

// Round 10
// 241.208 us; speedup vs baseline: 1.0908x; 1.0908x over previous
//
#include <hip/hip_runtime.h>

// ---------------------------------------------------------------------------
// Fused NeRF MLP forward: 262144 rows, 63-in, 8x256 hidden + skip at L4->L5,
// 4-dim output. fp16 MFMA (16x16x32) with fp32 accumulation.
//
// R10 = R8 (swapped-operand MFMA, packed b64 epilogue, bias-init acc,
// depth-3 W prefetch, nodrain barriers, setprio) + DOUBLE-BUFFERED hbuf:
//   layer reads hb[RB], writes hb[1-RB] -> the WAR barrier between main loop
//   and epilogue is eliminated; ONE barrier per layer (at layer end) instead
//   of two. LDS 76.8 KB -> 2 blocks/CU (8 waves). R5 proved occupancy above
//   12 waves/CU is non-binding; the bet is that halving the per-layer convoy
//   points (where all waves sit MFMA-idle in lockstep) raises MfmaUtil.
// R9 lesson: 32x32x16 (-13% matrix cycles) REGRESSED -> the matrix pipe is
// not the wall; reverted to 16x16x32.
// ---------------------------------------------------------------------------

typedef _Float16 h8 __attribute__((ext_vector_type(8)));
typedef float f4 __attribute__((ext_vector_type(4)));

// fragment-linear weight offsets, in halves:
// L0 K=64, L1..L4 K=256, L5 K=320, L6,L7 K=256, OUT K=256 (NF=1, n padded to 16)
#define OFF_L0   0
#define OFF_L1   16384
#define OFF_L2   81920
#define OFF_L3   147456
#define OFF_L4   212992
#define OFF_L5   278528
#define OFF_L6   360448
#define OFF_L7   425984
#define OFF_OUT  491520
#define TOT_HALVES 495616
#define TOT_GROUPS (TOT_HALVES / 8)   // 61952

__global__ void nerf_prep(const float* __restrict__ W0, const float* __restrict__ W1,
                          const float* __restrict__ W2, const float* __restrict__ W3,
                          const float* __restrict__ W4, const float* __restrict__ W5,
                          const float* __restrict__ W6, const float* __restrict__ W7,
                          const float* __restrict__ Wout, _Float16* __restrict__ wf)
{
    int g = blockIdx.x * 256 + threadIdx.x;     // one 8-half fragment group
    if (g >= TOT_GROUPS) return;

    const int bounds[10] = {0, 2048, 10240, 18432, 26624, 34816, 45056, 53248, 61440, 61952};
    const float* Ws[9] = {W0, W1, W2, W3, W4, W5, W6, W7, Wout};

    int L = 0;
    while (L < 8 && g >= bounds[L + 1]) ++L;

    int t    = g - bounds[L];
    int lane = t & 63;
    int q    = t >> 6;
    int NF   = (L == 8) ? 1 : 16;
    int nf   = q % NF;
    int ks   = q / NF;
    int n    = nf * 16 + (lane & 15);
    int k0   = ks * 32 + (lane >> 4) * 8;

    const float* W = Ws[L];
    h8 v;
#pragma unroll
    for (int i = 0; i < 8; ++i) {
        int k = k0 + i;
        float val = 0.f;
        if (L == 0) {
            if (k < 63) val = W[k * 256 + n];                 // 63x256, pad k=63
        } else if (L == 5) {
            // k' < 256 -> h part (orig row 63+k'); k' >= 256 -> x part (orig row k'-256)
            if (k < 256)             val = W[(63 + k) * 256 + n];
            else if ((k - 256) < 63) val = W[(k - 256) * 256 + n];
        } else if (L == 8) {
            if (n < 4) val = W[k * 4 + n];                    // 256x4, pad n to 16
        } else {
            val = W[k * 256 + n];                             // 256x256
        }
        v[i] = (_Float16)val;
    }
    *(h8*)(wf + (size_t)g * 8) = v;
}

__device__ __forceinline__ const h8* bfrag_ptr(const _Float16* __restrict__ w,
                                               int ks, int wid, int nf, int lane)
{
    return (const h8*)(w + (size_t)((ks * 16 + (wid * 4 + nf)) * 64 + lane) * 8);
}

// Barrier without vmcnt drain (keeps cross-layer W-prefetch loads in flight).
__device__ __forceinline__ void barrier_nodrain()
{
    asm volatile("s_waitcnt lgkmcnt(0)" ::: "memory");
    __builtin_amdgcn_s_barrier();
    __builtin_amdgcn_sched_barrier(0);
}

// MODE: 0 = h from rbuf, 1 = h from xbuf (layer 0), 2 = rbuf then xbuf (layer 5)
// Reads rbuf, writes wbuf (double-buffer) -> single barrier per layer.
// pf: depth-3 rolling W prefetch (slot = global kstep % 3, GB3 = gbase % 3).
template <int KSTEPS, int MODE, int GB3, bool LAST>
__device__ __forceinline__ void mlp_layer(const _Float16 (&rbuf)[64][264],
                                          _Float16 (&wbuf)[64][264],
                                          const _Float16 (&xbuf)[64][72],
                                          const _Float16* __restrict__ wfrag,
                                          const _Float16* __restrict__ wnext,
                                          const float* __restrict__ bias,
                                          int wid, int lane, h8 (&pf)[3][4])
{
    const int lg = lane >> 4, ln = lane & 15;

    // bias as float4 per cf: ncols wid*64 + cf*16 + lg*4 + (0..3)  (16B aligned)
    f4 bv[4];
#pragma unroll
    for (int cf = 0; cf < 4; ++cf)
        bv[cf] = *(const f4*)&bias[wid * 64 + cf * 16 + lg * 4];

    // accumulator INITIALIZED with bias (saves zero-init + epilogue add)
    f4 acc[4][4];   // [cf][sf]
#pragma unroll
    for (int cf = 0; cf < 4; ++cf)
#pragma unroll
        for (int sf = 0; sf < 4; ++sf)
            acc[cf][sf] = bv[cf];

#pragma unroll
    for (int ks = 0; ks < KSTEPS; ++ks) {
        const int slot = (GB3 + ks) % 3;      // folds to constant after unroll
        __builtin_amdgcn_s_setprio(1);
        h8 hfr[4];
#pragma unroll
        for (int sf = 0; sf < 4; ++sf) {
            const _Float16* ap;
            if constexpr (MODE == 1) {
                ap = &xbuf[sf * 16 + ln][ks * 32 + lg * 8];
            } else if constexpr (MODE == 2) {
                ap = (ks < 8) ? &rbuf[sf * 16 + ln][ks * 32 + lg * 8]
                              : &xbuf[sf * 16 + ln][(ks - 8) * 32 + lg * 8];
            } else {
                ap = &rbuf[sf * 16 + ln][ks * 32 + lg * 8];
            }
            hfr[sf] = *(const h8*)ap;
        }
#pragma unroll
        for (int cf = 0; cf < 4; ++cf)
#pragma unroll
            for (int sf = 0; sf < 4; ++sf)
                acc[cf][sf] = __builtin_amdgcn_mfma_f32_16x16x32_f16(pf[slot][cf], hfr[sf], acc[cf][sf], 0, 0, 0);
        __builtin_amdgcn_s_setprio(0);
        // refill the slot just consumed with global kstep g+3
        if (ks + 3 < KSTEPS) {
#pragma unroll
            for (int cf = 0; cf < 4; ++cf)
                pf[slot][cf] = *bfrag_ptr(wfrag, ks + 3, wid, cf, lane);
        } else {
            if constexpr (!LAST) {
#pragma unroll
                for (int cf = 0; cf < 4; ++cf)
                    pf[slot][cf] = *bfrag_ptr(wnext, ks + 3 - KSTEPS, wid, cf, lane);
            }
        }
    }

    // packed epilogue straight into the WRITE buffer (no WAR barrier needed):
    // D layout (m89): col=ln=sample-within-16, row=lg*4+reg=ncol-within-16
#pragma unroll
    for (int cf = 0; cf < 4; ++cf) {
#pragma unroll
        for (int sf = 0; sf < 4; ++sf) {
            union { _Float16 h[4]; unsigned long long u; } p;
#pragma unroll
            for (int i = 0; i < 4; ++i)
                p.h[i] = (_Float16)fmaxf(acc[cf][sf][i], 0.f);
            *(unsigned long long*)&wbuf[sf * 16 + ln][wid * 64 + cf * 16 + lg * 4] = p.u;
        }
    }
    barrier_nodrain();   // single barrier: wbuf complete before anyone reads it
}

__global__ __launch_bounds__(256, 2) void nerf_fused(
    const float* __restrict__ x,
    const float* __restrict__ b0, const float* __restrict__ b1, const float* __restrict__ b2,
    const float* __restrict__ b3, const float* __restrict__ b4, const float* __restrict__ b5,
    const float* __restrict__ b6, const float* __restrict__ b7, const float* __restrict__ bout,
    const _Float16* __restrict__ wf,
    float* __restrict__ out)
{
    __shared__ _Float16 hb[2][64][264];  // double-buffered activations (padded)
    __shared__ _Float16 xbuf[64][72];    // x (63 real + 1 zero) + pad

    const int tid  = threadIdx.x;
    const int wid  = tid >> 6;
    const int lane = tid & 63;
    const int lg   = lane >> 4, ln = lane & 15;
    const int row0 = blockIdx.x * 64;

    // prologue: globals 0,1,2 = L0 ks0, L0 ks1, L1 ks0 into slots 0,1,2
    h8 pf[3][4];
#pragma unroll
    for (int cf = 0; cf < 4; ++cf) {
        pf[0][cf] = *bfrag_ptr(wf + OFF_L0, 0, wid, cf, lane);
        pf[1][cf] = *bfrag_ptr(wf + OFF_L0, 1, wid, cf, lane);
        pf[2][cf] = *bfrag_ptr(wf + OFF_L1, 0, wid, cf, lane);
    }

    // stage x[:, 0:63] -> fp16, zero-pad col 63
    for (int idx = tid; idx < 64 * 64; idx += 256) {
        int r = idx >> 6, c = idx & 63;
        float v = (c < 63) ? x[(size_t)(row0 + r) * 90 + c] : 0.f;
        xbuf[r][c] = (_Float16)v;
    }
    barrier_nodrain();

    // buffers: L0 w0; L1 r0 w1; L2 r1 w0; L3 r0 w1; L4 r1 w0; L5 r0 w1;
    //          L6 r1 w0; L7 r0 w1; out reads hb[1].
    // gbase per layer: 0,2,10,18,26,34,44,52 -> %3 = 0,2,1,0,2,1,2,1
    mlp_layer<2,  1, 0, false>(hb[0], hb[0], xbuf, wf + OFF_L0, wf + OFF_L1, b0, wid, lane, pf);
    mlp_layer<8,  0, 2, false>(hb[0], hb[1], xbuf, wf + OFF_L1, wf + OFF_L2, b1, wid, lane, pf);
    mlp_layer<8,  0, 1, false>(hb[1], hb[0], xbuf, wf + OFF_L2, wf + OFF_L3, b2, wid, lane, pf);
    mlp_layer<8,  0, 0, false>(hb[0], hb[1], xbuf, wf + OFF_L3, wf + OFF_L4, b3, wid, lane, pf);
    mlp_layer<8,  0, 2, false>(hb[1], hb[0], xbuf, wf + OFF_L4, wf + OFF_L5, b4, wid, lane, pf);
    mlp_layer<10, 2, 1, false>(hb[0], hb[1], xbuf, wf + OFF_L5, wf + OFF_L6, b5, wid, lane, pf);
    mlp_layer<8,  0, 2, false>(hb[1], hb[0], xbuf, wf + OFF_L6, wf + OFF_L7, b6, wid, lane, pf);
    mlp_layer<8,  0, 1, true >(hb[0], hb[1], xbuf, wf + OFF_L7, wf + OFF_L7, b7, wid, lane, pf);

    // output layer 256 -> 4 (padded to 16 cols), UNswapped (original path):
    // wave wid owns rows [16*wid, 16*wid+16); reads hb[1] (L7's output)
    f4 oacc;
#pragma unroll
    for (int i = 0; i < 4; ++i) oacc[i] = 0.f;
#pragma unroll
    for (int ks = 0; ks < 8; ++ks) {
        h8 bfr = *(const h8*)(wf + OFF_OUT + (size_t)(ks * 64 + lane) * 8);
        h8 afr = *(const h8*)&hb[1][wid * 16 + ln][ks * 32 + lg * 8];
        oacc = __builtin_amdgcn_mfma_f32_16x16x32_f16(afr, bfr, oacc, 0, 0, 0);
    }
    if (ln < 4) {
        float bo = bout[ln];
#pragma unroll
        for (int i = 0; i < 4; ++i) {
            int r = row0 + wid * 16 + lg * 4 + i;
            out[(size_t)r * 4 + ln] = oacc[i] + bo;
        }
    }
}

extern "C" void kernel_launch(void* const* d_in, const int* in_sizes, int n_in,
                              void* d_out, int out_size, void* d_ws, size_t ws_size,
                              hipStream_t stream)
{
    const float* x = (const float*)d_in[0];
    const float* W[9];
    const float* b[9];
    for (int i = 0; i < 8; ++i) {
        W[i] = (const float*)d_in[1 + 2 * i];
        b[i] = (const float*)d_in[2 + 2 * i];
    }
    W[8] = (const float*)d_in[17];   // Wout
    b[8] = (const float*)d_in[18];   // bout

    _Float16* wf = (_Float16*)d_ws;

    nerf_prep<<<(TOT_GROUPS + 255) / 256, 256, 0, stream>>>(
        W[0], W[1], W[2], W[3], W[4], W[5], W[6], W[7], W[8], wf);

    nerf_fused<<<262144 / 64, 256, 0, stream>>>(
        x, b[0], b[1], b[2], b[3], b[4], b[5], b[6], b[7], b[8], wf,
        (float*)d_out);
}